// Round 1
// baseline (953.094 us; speedup 1.0000x reference)
//
#include <hip/hip_runtime.h>
#include <cstdint>

constexpr int B  = 64;
constexpr int N  = 1723;
constexpr int E  = 1723;
constexpr int NNZ = 16384;
constexpr int ROWS = B * N;   // 110272 = 64*1723, divisible by 64

// ---------------- workspace layout ----------------
// int region (element offsets into (int*)ws):
constexpr size_t OFF_DD   = 0;                   // int[E]   node degree counts
constexpr size_t OFF_BD   = OFF_DD + E;          // int[E]   edge degree counts
constexpr size_t OFF_NCUR = OFF_BD + E;          // int[E]
constexpr size_t OFF_ECUR = OFF_NCUR + E;        // int[E]
constexpr size_t OFF_NOFF = OFF_ECUR + E;        // int[E+1]
constexpr size_t OFF_EOFF = OFF_NOFF + (E + 1);  // int[E+1]
constexpr size_t OFF_NVAL = OFF_EOFF + (E + 1);  // int[NNZ]
constexpr size_t OFF_EVAL = OFF_NVAL + NNZ;      // int[NNZ]

// byte offsets for float buffers:
constexpr size_t B_STATS = 262144;                                        // float2[ROWS]
constexpr size_t B_SLOTA = B_STATS + (((size_t)ROWS * 8 + 4095) / 4096) * 4096;
constexpr size_t SLOT_BIG = (size_t)ROWS * 128 * 4;                       // 56,459,264 B
constexpr size_t B_SLOTB = B_SLOTA + SLOT_BIG;
constexpr size_t B_SLOTC = B_SLOTB + SLOT_BIG;
constexpr size_t B_SLOTD = B_SLOTC + SLOT_BIG;                            // y2 (14.1 MB)

// ---------------- CSR build ----------------
__global__ __launch_bounds__(256) void k_hist(const int* __restrict__ inc,
                                              int* __restrict__ Dd, int* __restrict__ Bd) {
  int k = blockIdx.x * 256 + threadIdx.x;           // grid exact: NNZ/256
  atomicAdd(&Dd[inc[k]], 1);
  atomicAdd(&Bd[inc[NNZ + k]], 1);
}

__global__ __launch_bounds__(256) void k_scan(const int* __restrict__ Dd, const int* __restrict__ Bd,
                                              int* __restrict__ noff, int* __restrict__ eoff) {
  __shared__ int part[256];
  const int t = threadIdx.x;
  for (int pass = 0; pass < 2; ++pass) {
    const int* cnt = pass ? Bd : Dd;
    int* off = pass ? eoff : noff;
    constexpr int CH = 7;  // 256*7 = 1792 >= 1723
    int loc[CH];
    int s = 0;
    int base = t * CH;
#pragma unroll
    for (int i = 0; i < CH; ++i) {
      int idx = base + i;
      loc[i] = (idx < E) ? cnt[idx] : 0;
      s += loc[i];
    }
    part[t] = s;
    __syncthreads();
    for (int d = 1; d < 256; d <<= 1) {
      int v = (t >= d) ? part[t - d] : 0;
      __syncthreads();
      part[t] += v;
      __syncthreads();
    }
    int pre = (t > 0) ? part[t - 1] : 0;
#pragma unroll
    for (int i = 0; i < CH; ++i) {
      int idx = base + i;
      if (idx < E) off[idx] = pre;
      pre += loc[i];
    }
    if (t == 255) off[E] = pre;   // = NNZ
    __syncthreads();
  }
}

__global__ __launch_bounds__(256) void k_fill(const int* __restrict__ inc,
                                              const int* __restrict__ noff, const int* __restrict__ eoff,
                                              int* __restrict__ ncur, int* __restrict__ ecur,
                                              int* __restrict__ nval, int* __restrict__ eval) {
  int k = blockIdx.x * 256 + threadIdx.x;
  int n = inc[k], e = inc[NNZ + k];
  int p = atomicAdd(&ecur[e], 1);
  eval[eoff[e] + p] = n;
  int q = atomicAdd(&ncur[n], 1);
  nval[noff[n] + q] = e;
}

// deterministic ordering (and mild gather locality): sort each segment
__global__ __launch_bounds__(256) void k_sort(const int* __restrict__ off, int* __restrict__ vals) {
  int s = blockIdx.x * 256 + threadIdx.x;
  if (s >= E) return;
  int b = off[s], e = off[s + 1];
  for (int i = b + 1; i < e; ++i) {
    int v = vals[i];
    int j = i - 1;
    while (j >= b && vals[j] > v) { vals[j + 1] = vals[j]; --j; }
    vals[j + 1] = v;
  }
}

// ---------------- per-row LN stats (mu, rsqrt(var+eps)) ----------------
template <int K>
__global__ __launch_bounds__(256) void row_stats_k(const float* __restrict__ in,
                                                   float2* __restrict__ stats) {
  constexpr int VEC = K / 64;  // 4, 2, or 1
  int lane = threadIdx.x & 63;
  int wave = threadIdx.x >> 6;
  int row = blockIdx.x * 4 + wave;     // grid exact: ROWS/4
  const float* src = in + (size_t)row * K + lane * VEC;
  float v[VEC];
  if constexpr (VEC == 4) {
    float4 t = *(const float4*)src;
    v[0] = t.x; v[1] = t.y; v[2] = t.z; v[3] = t.w;
  } else if constexpr (VEC == 2) {
    float2 t = *(const float2*)src;
    v[0] = t.x; v[1] = t.y;
  } else {
    v[0] = *src;
  }
  float s1 = 0.f, s2 = 0.f;
#pragma unroll
  for (int j = 0; j < VEC; ++j) { s1 += v[j]; s2 += v[j] * v[j]; }
#pragma unroll
  for (int off = 32; off > 0; off >>= 1) {
    s1 += __shfl_xor(s1, off, 64);
    s2 += __shfl_xor(s2, off, 64);
  }
  if (lane == 0) {
    float mu = s1 / K;
    float var = fmaxf(s2 / K - mu * mu, 0.f);
    stats[row] = make_float2(mu, rsqrtf(var + 1e-5f));
  }
}

// ---------------- fused (LN+relu on A) GEMM:  out[r][c] = sum_k A'[r][k]*W[c][k] (+bias) ----------------
// OUTMODE 0: out idx = r*NOUT + c                          (r unchanged)
// OUTMODE 1: r = b*N+n  ->  out idx = (n*B+b)*NOUT + c     (to node-major layout)
// OUTMODE 2: r = n*B+b  ->  out idx = (b*N+n)*NOUT + c, plus skip[idx]
template <int K, int NOUT, int BN, int MN, int OUTMODE, bool LNA, bool BIAS>
__global__ __launch_bounds__(256) void gemm_k(const float* __restrict__ A,
                                              const float* __restrict__ W,
                                              const float* __restrict__ bias,
                                              const float2* __restrict__ stats,
                                              const float* __restrict__ g,
                                              const float* __restrict__ be,
                                              const float* __restrict__ skip,
                                              float* __restrict__ out) {
  constexpr int BM = 64;
  constexpr int BK = (K < 64) ? K : 64;
  constexpr int LDA = BK + 4;          // pad -> <=2-way LDS bank aliasing (free)
  constexpr int BK4 = BK / 4;
  constexpr int A_PT = BM * BK4 / 256;
  constexpr int W_PT = BN * BK4 / 256;
  __shared__ float As[BM][LDA];
  __shared__ float Ws[BN][LDA];
  const int t = threadIdx.x;
  const int r0 = blockIdx.x * BM;
  const int c0 = blockIdx.y * BN;
  const int tx = t & 15, ty = t >> 4;

  float acc[4][MN];
#pragma unroll
  for (int i = 0; i < 4; ++i)
#pragma unroll
    for (int j = 0; j < MN; ++j) acc[i][j] = 0.f;

  for (int k0 = 0; k0 < K; k0 += BK) {
#pragma unroll
    for (int i = 0; i < A_PT; ++i) {
      int idx = t + i * 256;
      int row = idx / BK4, c4 = idx % BK4;
      float4 v = *(const float4*)(A + (size_t)(r0 + row) * K + k0 + c4 * 4);
      if constexpr (LNA) {
        float2 st = stats[r0 + row];
        float4 gg = *(const float4*)(g + k0 + c4 * 4);
        float4 bb = *(const float4*)(be + k0 + c4 * 4);
        v.x = fmaxf(fmaf((v.x - st.x) * st.y, gg.x, bb.x), 0.f);
        v.y = fmaxf(fmaf((v.y - st.x) * st.y, gg.y, bb.y), 0.f);
        v.z = fmaxf(fmaf((v.z - st.x) * st.y, gg.z, bb.z), 0.f);
        v.w = fmaxf(fmaf((v.w - st.x) * st.y, gg.w, bb.w), 0.f);
      }
      *(float4*)&As[row][c4 * 4] = v;
    }
#pragma unroll
    for (int i = 0; i < W_PT; ++i) {
      int idx = t + i * 256;
      int row = idx / BK4, c4 = idx % BK4;
      *(float4*)&Ws[row][c4 * 4] = *(const float4*)(W + (size_t)(c0 + row) * K + k0 + c4 * 4);
    }
    __syncthreads();
#pragma unroll
    for (int kk = 0; kk < BK; kk += 4) {
      float4 a[4], w[MN];
#pragma unroll
      for (int i = 0; i < 4; ++i) a[i] = *(const float4*)&As[ty * 4 + i][kk];
#pragma unroll
      for (int j = 0; j < MN; ++j) w[j] = *(const float4*)&Ws[tx + j * 16][kk];
#pragma unroll
      for (int i = 0; i < 4; ++i)
#pragma unroll
        for (int j = 0; j < MN; ++j)
          acc[i][j] += a[i].x * w[j].x + a[i].y * w[j].y + a[i].z * w[j].z + a[i].w * w[j].w;
    }
    __syncthreads();
  }

#pragma unroll
  for (int i = 0; i < 4; ++i) {
    int r = r0 + ty * 4 + i;
    size_t obase;
    if constexpr (OUTMODE == 0) {
      obase = (size_t)r * NOUT;
    } else if constexpr (OUTMODE == 1) {
      int b_ = r / N;
      int n_ = r - b_ * N;
      obase = ((size_t)n_ * B + b_) * NOUT;
    } else {
      int n_ = r >> 6;          // r = n*B + b, B = 64
      int b_ = r & 63;
      obase = ((size_t)b_ * N + n_) * NOUT;
    }
#pragma unroll
    for (int j = 0; j < MN; ++j) {
      int c = c0 + tx + j * 16;
      float v = acc[i][j];
      if constexpr (BIAS) v += bias[c];
      if constexpr (OUTMODE == 2) v += skip[obase + c];
      out[obase + c] = v;
    }
  }
}

// ---------------- hypergraph aggregation (gather over CSR segment) ----------------
// edge pass:  ef[e][b][c] = (1/deg_e) * sum_{n in seg(e)} in[n][b][c]
// node pass:  out[n][b][c] = (1/deg_n) * sum_{e in seg(n)} in[e][b][c] + bias[c]
template <int C, bool ISNODE>
__global__ __launch_bounds__(256) void agg_k(const float* __restrict__ in,
                                             const int* __restrict__ off,
                                             const int* __restrict__ vals,
                                             const float* __restrict__ bias,
                                             float* __restrict__ outbuf) {
  constexpr int T4 = B * C / 4;
  constexpr int PT = T4 / 256;
  int seg = blockIdx.x;
  int beg = off[seg], end = off[seg + 1];
  float4 acc[PT];
#pragma unroll
  for (int i = 0; i < PT; ++i) acc[i] = make_float4(0.f, 0.f, 0.f, 0.f);
  for (int k = beg; k < end; ++k) {
    int src = vals[k];
    const float4* p = (const float4*)(in + (size_t)src * (B * C));
#pragma unroll
    for (int i = 0; i < PT; ++i) {
      float4 v = p[threadIdx.x + i * 256];
      acc[i].x += v.x; acc[i].y += v.y; acc[i].z += v.z; acc[i].w += v.w;
    }
  }
  float inv = (end > beg) ? 1.f / (float)(end - beg) : 0.f;
  float4* q = (float4*)(outbuf + (size_t)seg * (B * C));
#pragma unroll
  for (int i = 0; i < PT; ++i) {
    int f4 = threadIdx.x + i * 256;
    float4 r;
    r.x = acc[i].x * inv; r.y = acc[i].y * inv; r.z = acc[i].z * inv; r.w = acc[i].w * inv;
    if constexpr (ISNODE) {
      float4 bb = *(const float4*)(bias + (f4 % (C / 4)) * 4);
      r.x += bb.x; r.y += bb.y; r.z += bb.z; r.w += bb.w;
    }
    q[f4] = r;
  }
}

// ---------------- launch ----------------
extern "C" void kernel_launch(void* const* d_in, const int* in_sizes, int n_in,
                              void* d_out, int out_size, void* d_ws, size_t ws_size,
                              hipStream_t stream) {
  const float* x      = (const float*)d_in[0];
  const int*   inc    = (const int*)  d_in[1];
  const float* pre_g  = (const float*)d_in[2];
  const float* pre_b  = (const float*)d_in[3];
  const float* lin1_W = (const float*)d_in[4];
  const float* lin1_b = (const float*)d_in[5];
  const float* n1_g   = (const float*)d_in[6];
  const float* n1_b   = (const float*)d_in[7];
  const float* th1    = (const float*)d_in[8];
  const float* bi1    = (const float*)d_in[9];
  const float* th2    = (const float*)d_in[10];
  const float* bi2    = (const float*)d_in[11];
  const float* n2_g   = (const float*)d_in[12];
  const float* n2_b   = (const float*)d_in[13];
  const float* lin2_W = (const float*)d_in[14];
  const float* lin2_b = (const float*)d_in[15];
  float* out = (float*)d_out;
  char* ws = (char*)d_ws;

  int* meta = (int*)ws;
  int* Dd   = meta + OFF_DD;
  int* Bd   = meta + OFF_BD;
  int* ncur = meta + OFF_NCUR;
  int* ecur = meta + OFF_ECUR;
  int* noff = meta + OFF_NOFF;
  int* eoff = meta + OFF_EOFF;
  int* nval = meta + OFF_NVAL;
  int* eval = meta + OFF_EVAL;

  float2* stats = (float2*)(ws + B_STATS);
  float* slotA = (float*)(ws + B_SLOTA);
  float* slotB = (float*)(ws + B_SLOTB);
  float* slotC = (float*)(ws + B_SLOTC);
  float* slotD = (float*)(ws + B_SLOTD);
  float* y1  = slotA;  // (ROWS,64), rows = n*B+b
  float* xl2 = slotA;  // (ROWS,128) — y1 dead by then
  float* xl1 = slotB;  // (ROWS,32)
  float* ef2 = slotB;  // (E,B,128) — xl1 dead by then
  float* ef1 = slotC;  // (E,B,32)
  float* y3  = slotC;  // (ROWS,128) — ef1 dead by then
  float* y2  = slotD;  // (ROWS,32)

  // zero degree counters + cursors (contiguous 4*E ints)
  hipMemsetAsync(ws, 0, (size_t)4 * E * sizeof(int), stream);

  k_hist<<<NNZ / 256, 256, 0, stream>>>(inc, Dd, Bd);
  k_scan<<<1, 256, 0, stream>>>(Dd, Bd, noff, eoff);
  k_fill<<<NNZ / 256, 256, 0, stream>>>(inc, noff, eoff, ncur, ecur, nval, eval);
  k_sort<<<(E + 255) / 256, 256, 0, stream>>>(noff, nval);
  k_sort<<<(E + 255) / 256, 256, 0, stream>>>(eoff, eval);

  // ty = relu(LN(x)); y1 = lin1(ty)  -> rows permuted to n*B+b
  row_stats_k<256><<<ROWS / 4, 256, 0, stream>>>(x, stats);
  gemm_k<256, 64, 64, 4, 1, true, true>
      <<<dim3(ROWS / 64, 1), 256, 0, stream>>>(x, lin1_W, lin1_b, stats, pre_g, pre_b, nullptr, y1);

  // xl1 = theta1( relu(LN(y1)) )
  row_stats_k<64><<<ROWS / 4, 256, 0, stream>>>(y1, stats);
  gemm_k<64, 32, 32, 2, 0, true, false>
      <<<dim3(ROWS / 64, 1), 256, 0, stream>>>(y1, th1, nullptr, stats, n1_g, n1_b, nullptr, xl1);

  // hconv1 propagation
  agg_k<32, false><<<E, 256, 0, stream>>>(xl1, eoff, eval, nullptr, ef1);
  agg_k<32, true ><<<E, 256, 0, stream>>>(ef1, noff, nval, bi1, y2);

  // xl2 = theta2(y2)
  gemm_k<32, 128, 128, 8, 0, false, false>
      <<<dim3(ROWS / 64, 1), 256, 0, stream>>>(y2, th2, nullptr, nullptr, nullptr, nullptr, nullptr, xl2);

  // hconv2 propagation
  agg_k<128, false><<<E, 256, 0, stream>>>(xl2, eoff, eval, nullptr, ef2);
  agg_k<128, true ><<<E, 256, 0, stream>>>(ef2, noff, nval, bi2, y3);

  // out = x + lin2( relu(LN(y3)) )
  row_stats_k<128><<<ROWS / 4, 256, 0, stream>>>(y3, stats);
  gemm_k<128, 256, 128, 8, 2, true, true>
      <<<dim3(ROWS / 64, 2), 256, 0, stream>>>(y3, lin2_W, lin2_b, stats, n2_g, n2_b, x, out);
}

// Round 2
// 434.124 us; speedup vs baseline: 2.1954x; 2.1954x over previous
//
#include <hip/hip_runtime.h>
#include <cstdint>

constexpr int B  = 64;
constexpr int N  = 1723;
constexpr int E  = 1723;
constexpr int NNZ = 16384;
constexpr int ROWS = B * N;   // 110272 = 64*1723

typedef __bf16 bf16x8 __attribute__((ext_vector_type(8)));
typedef float  f32x4  __attribute__((ext_vector_type(4)));

// ---------------- workspace layout ----------------
constexpr size_t OFF_DD   = 0;
constexpr size_t OFF_BD   = OFF_DD + E;
constexpr size_t OFF_NCUR = OFF_BD + E;
constexpr size_t OFF_ECUR = OFF_NCUR + E;
constexpr size_t OFF_NOFF = OFF_ECUR + E;
constexpr size_t OFF_EOFF = OFF_NOFF + (E + 1);
constexpr size_t OFF_NVAL = OFF_EOFF + (E + 1);
constexpr size_t OFF_EVAL = OFF_NVAL + NNZ;

constexpr size_t B_STATS = 262144;                                        // float2[ROWS]
constexpr size_t B_SLOTA = B_STATS + (((size_t)ROWS * 8 + 4095) / 4096) * 4096;
constexpr size_t SLOT_BIG = (size_t)ROWS * 128 * 4;
constexpr size_t B_SLOTB = B_SLOTA + SLOT_BIG;
constexpr size_t B_SLOTC = B_SLOTB + SLOT_BIG;
constexpr size_t B_SLOTD = B_SLOTC + SLOT_BIG;

// ---------------- CSR build ----------------
__global__ __launch_bounds__(256) void k_hist(const int* __restrict__ inc,
                                              int* __restrict__ Dd, int* __restrict__ Bd) {
  int k = blockIdx.x * 256 + threadIdx.x;
  atomicAdd(&Dd[inc[k]], 1);
  atomicAdd(&Bd[inc[NNZ + k]], 1);
}

__global__ __launch_bounds__(256) void k_scan(const int* __restrict__ Dd, const int* __restrict__ Bd,
                                              int* __restrict__ noff, int* __restrict__ eoff) {
  __shared__ int part[256];
  const int t = threadIdx.x;
  for (int pass = 0; pass < 2; ++pass) {
    const int* cnt = pass ? Bd : Dd;
    int* off = pass ? eoff : noff;
    constexpr int CH = 7;
    int loc[CH];
    int s = 0;
    int base = t * CH;
#pragma unroll
    for (int i = 0; i < CH; ++i) {
      int idx = base + i;
      loc[i] = (idx < E) ? cnt[idx] : 0;
      s += loc[i];
    }
    part[t] = s;
    __syncthreads();
    for (int d = 1; d < 256; d <<= 1) {
      int v = (t >= d) ? part[t - d] : 0;
      __syncthreads();
      part[t] += v;
      __syncthreads();
    }
    int pre = (t > 0) ? part[t - 1] : 0;
#pragma unroll
    for (int i = 0; i < CH; ++i) {
      int idx = base + i;
      if (idx < E) off[idx] = pre;
      pre += loc[i];
    }
    if (t == 255) off[E] = pre;
    __syncthreads();
  }
}

__global__ __launch_bounds__(256) void k_fill(const int* __restrict__ inc,
                                              const int* __restrict__ noff, const int* __restrict__ eoff,
                                              int* __restrict__ ncur, int* __restrict__ ecur,
                                              int* __restrict__ nval, int* __restrict__ eval) {
  int k = blockIdx.x * 256 + threadIdx.x;
  int n = inc[k], e = inc[NNZ + k];
  int p = atomicAdd(&ecur[e], 1);
  eval[eoff[e] + p] = n;
  int q = atomicAdd(&ncur[n], 1);
  nval[noff[n] + q] = e;
}

__global__ __launch_bounds__(256) void k_sort(const int* __restrict__ off, int* __restrict__ vals) {
  int s = blockIdx.x * 256 + threadIdx.x;
  if (s >= E) return;
  int b = off[s], e = off[s + 1];
  for (int i = b + 1; i < e; ++i) {
    int v = vals[i];
    int j = i - 1;
    while (j >= b && vals[j] > v) { vals[j + 1] = vals[j]; --j; }
    vals[j + 1] = v;
  }
}

// ---------------- per-row LN stats ----------------
template <int K>
__global__ __launch_bounds__(256) void row_stats_k(const float* __restrict__ in,
                                                   float2* __restrict__ stats) {
  constexpr int VEC = K / 64;
  int lane = threadIdx.x & 63;
  int wave = threadIdx.x >> 6;
  int row = blockIdx.x * 4 + wave;
  const float* src = in + (size_t)row * K + lane * VEC;
  float v[VEC];
  if constexpr (VEC == 4) {
    float4 t = *(const float4*)src;
    v[0] = t.x; v[1] = t.y; v[2] = t.z; v[3] = t.w;
  } else if constexpr (VEC == 2) {
    float2 t = *(const float2*)src;
    v[0] = t.x; v[1] = t.y;
  } else {
    v[0] = *src;
  }
  float s1 = 0.f, s2 = 0.f;
#pragma unroll
  for (int j = 0; j < VEC; ++j) { s1 += v[j]; s2 += v[j] * v[j]; }
#pragma unroll
  for (int off = 32; off > 0; off >>= 1) {
    s1 += __shfl_xor(s1, off, 64);
    s2 += __shfl_xor(s2, off, 64);
  }
  if (lane == 0) {
    float mu = s1 / K;
    float var = fmaxf(s2 / K - mu * mu, 0.f);
    stats[row] = make_float2(mu, rsqrtf(var + 1e-5f));
  }
}

// ---------------- bf16 MFMA GEMM, fused LN/relu on A, coalesced epilogue ----------------
__device__ __forceinline__ ushort f2bf(float f) {
  uint32_t b = __float_as_uint(f);
  b += 0x7fffu + ((b >> 16) & 1u);
  return (ushort)(b >> 16);
}

union U16x8 { uint4 q; ushort s[8]; };

// out[r][c] = sum_k act(A[r][k]) * W[c][k] (+bias) (+skip), row remap per OUTMODE
// OUTMODE 0: row unchanged; 1: r=b*N+n -> (n*B+b); 2: r=n*B+b -> (b*N+n)
template <int K, int NOUT, int OUTMODE, bool LNA, bool BIAS, bool SKIP>
__global__ __launch_bounds__(256, 2) void gemm_mfma(const float* __restrict__ A,
                                                    const float* __restrict__ W,
                                                    const float* __restrict__ bias,
                                                    const float2* __restrict__ stats,
                                                    const float* __restrict__ g,
                                                    const float* __restrict__ be,
                                                    const float* __restrict__ skip,
                                                    float* __restrict__ out) {
  constexpr int CPR = K / 8;                       // 16B bf16 chunks per row
  constexpr int CMASK = (CPR >= 8) ? 7 : (CPR - 1);
  constexpr int SSTG = (64 + NOUT) * K * 2;
  constexpr int SOUT = 64 * (NOUT + 4) * 4;
  constexpr int SMEM = (SSTG > SOUT) ? SSTG : SOUT;
  __shared__ __align__(16) char smem[SMEM];
  uint4* AsQ = (uint4*)smem;                       // [64*CPR]
  uint4* WsQ = AsQ + 64 * CPR;                     // [NOUT*CPR]

  const int t = threadIdx.x;
  const int r0 = blockIdx.x * 64;

  // ---- stage A (LN+relu+cvt) ----
#pragma unroll
  for (int i = 0; i < 64 * CPR / 256; ++i) {
    int idx = t + i * 256;
    int row = idx / CPR, c = idx % CPR;
    const float* src = A + (size_t)(r0 + row) * K + c * 8;
    float4 v0 = *(const float4*)src;
    float4 v1 = *(const float4*)(src + 4);
    if constexpr (LNA) {
      float2 st = stats[r0 + row];
      float4 g0 = *(const float4*)(g + c * 8);
      float4 g1 = *(const float4*)(g + c * 8 + 4);
      float4 b0 = *(const float4*)(be + c * 8);
      float4 b1 = *(const float4*)(be + c * 8 + 4);
      v0.x = fmaxf(fmaf((v0.x - st.x) * st.y, g0.x, b0.x), 0.f);
      v0.y = fmaxf(fmaf((v0.y - st.x) * st.y, g0.y, b0.y), 0.f);
      v0.z = fmaxf(fmaf((v0.z - st.x) * st.y, g0.z, b0.z), 0.f);
      v0.w = fmaxf(fmaf((v0.w - st.x) * st.y, g0.w, b0.w), 0.f);
      v1.x = fmaxf(fmaf((v1.x - st.x) * st.y, g1.x, b1.x), 0.f);
      v1.y = fmaxf(fmaf((v1.y - st.x) * st.y, g1.y, b1.y), 0.f);
      v1.z = fmaxf(fmaf((v1.z - st.x) * st.y, g1.z, b1.z), 0.f);
      v1.w = fmaxf(fmaf((v1.w - st.x) * st.y, g1.w, b1.w), 0.f);
    }
    U16x8 u;
    u.s[0] = f2bf(v0.x); u.s[1] = f2bf(v0.y); u.s[2] = f2bf(v0.z); u.s[3] = f2bf(v0.w);
    u.s[4] = f2bf(v1.x); u.s[5] = f2bf(v1.y); u.s[6] = f2bf(v1.z); u.s[7] = f2bf(v1.w);
    AsQ[row * CPR + (c ^ (row & CMASK))] = u.q;
  }
  // ---- stage W (cvt) ----
#pragma unroll
  for (int i = 0; i < NOUT * CPR / 256; ++i) {
    int idx = t + i * 256;
    int row = idx / CPR, c = idx % CPR;
    const float* src = W + (size_t)row * K + c * 8;
    float4 v0 = *(const float4*)src;
    float4 v1 = *(const float4*)(src + 4);
    U16x8 u;
    u.s[0] = f2bf(v0.x); u.s[1] = f2bf(v0.y); u.s[2] = f2bf(v0.z); u.s[3] = f2bf(v0.w);
    u.s[4] = f2bf(v1.x); u.s[5] = f2bf(v1.y); u.s[6] = f2bf(v1.z); u.s[7] = f2bf(v1.w);
    WsQ[row * CPR + (c ^ (row & CMASK))] = u.q;
  }
  __syncthreads();

  // ---- MFMA: 4 waves as 2(M) x 2(N) ----
  const int lane = t & 63;
  const int w = t >> 6;
  const int lo = lane & 15, hi = lane >> 4;
  const int wm = w & 1, wn = w >> 1;
  constexpr int NF2 = NOUT / 32;
  f32x4 acc[2][NF2] = {};
  const int m0 = wm * 32 + lo;
  const int m1 = wm * 32 + 16 + lo;
  const bf16x8* Asv = (const bf16x8*)AsQ;
  const bf16x8* Wsv = (const bf16x8*)WsQ;
#pragma unroll
  for (int ks = 0; ks < K / 32; ++ks) {
    int cb = ks * 4 + hi;
    bf16x8 a0 = Asv[m0 * CPR + (cb ^ (m0 & CMASK))];
    bf16x8 a1 = Asv[m1 * CPR + (cb ^ (m1 & CMASK))];
#pragma unroll
    for (int f = 0; f < NF2; ++f) {
      int n = wn * (NOUT / 2) + f * 16 + lo;
      bf16x8 bfr = Wsv[n * CPR + (cb ^ (n & CMASK))];
      acc[0][f] = __builtin_amdgcn_mfma_f32_16x16x32_bf16(a0, bfr, acc[0][f], 0, 0, 0);
      acc[1][f] = __builtin_amdgcn_mfma_f32_16x16x32_bf16(a1, bfr, acc[1][f], 0, 0, 0);
    }
  }
  __syncthreads();   // all frag reads done; reuse LDS for epilogue

  // ---- acc -> LDS (D layout: col=lane&15, row=(lane>>4)*4+reg) ----
  float* ost = (float*)smem;
  constexpr int OLD = NOUT + 4;
#pragma unroll
  for (int i = 0; i < 2; ++i) {
#pragma unroll
    for (int f = 0; f < NF2; ++f) {
      int col = wn * (NOUT / 2) + f * 16 + lo;
      float badd = BIAS ? bias[col] : 0.f;
#pragma unroll
      for (int r = 0; r < 4; ++r) {
        int lr = wm * 32 + i * 16 + hi * 4 + r;
        ost[lr * OLD + col] = acc[i][f][r] + badd;
      }
    }
  }
  __syncthreads();

  // ---- coalesced row writes ----
  constexpr int F4PR = NOUT / 4;
#pragma unroll
  for (int i = 0; i < NOUT / 16; ++i) {
    int idx = t + i * 256;
    int lr = idx / F4PR, c4 = idx % F4PR;
    uint32_t r = r0 + lr;
    size_t obase;
    if constexpr (OUTMODE == 0) {
      obase = (size_t)r * NOUT;
    } else if constexpr (OUTMODE == 1) {
      uint32_t b_ = r / (uint32_t)N;
      uint32_t n_ = r - b_ * (uint32_t)N;
      obase = ((size_t)n_ * B + b_) * NOUT;
    } else {
      uint32_t n_ = r >> 6;
      uint32_t b_ = r & 63u;
      obase = ((size_t)b_ * N + n_) * NOUT;
    }
    float4 v = *(const float4*)&ost[lr * OLD + c4 * 4];
    if constexpr (SKIP) {
      float4 s = *(const float4*)(skip + obase + c4 * 4);
      v.x += s.x; v.y += s.y; v.z += s.z; v.w += s.w;
    }
    *(float4*)(out + obase + c4 * 4) = v;
  }
}

// ---------------- hypergraph aggregation (gather over CSR segment) ----------------
template <int C, bool ISNODE>
__global__ __launch_bounds__(256) void agg_k(const float* __restrict__ in,
                                             const int* __restrict__ off,
                                             const int* __restrict__ vals,
                                             const float* __restrict__ bias,
                                             float* __restrict__ outbuf) {
  constexpr int T4 = B * C / 4;
  constexpr int PT = T4 / 256;
  int seg = blockIdx.x;
  int beg = off[seg], end = off[seg + 1];
  float4 acc[PT];
#pragma unroll
  for (int i = 0; i < PT; ++i) acc[i] = make_float4(0.f, 0.f, 0.f, 0.f);
  for (int k = beg; k < end; ++k) {
    int src = vals[k];
    const float4* p = (const float4*)(in + (size_t)src * (B * C));
#pragma unroll
    for (int i = 0; i < PT; ++i) {
      float4 v = p[threadIdx.x + i * 256];
      acc[i].x += v.x; acc[i].y += v.y; acc[i].z += v.z; acc[i].w += v.w;
    }
  }
  float inv = (end > beg) ? 1.f / (float)(end - beg) : 0.f;
  float4* q = (float4*)(outbuf + (size_t)seg * (B * C));
#pragma unroll
  for (int i = 0; i < PT; ++i) {
    int f4 = threadIdx.x + i * 256;
    float4 r;
    r.x = acc[i].x * inv; r.y = acc[i].y * inv; r.z = acc[i].z * inv; r.w = acc[i].w * inv;
    if constexpr (ISNODE) {
      float4 bb = *(const float4*)(bias + (f4 % (C / 4)) * 4);
      r.x += bb.x; r.y += bb.y; r.z += bb.z; r.w += bb.w;
    }
    q[f4] = r;
  }
}

// ---------------- launch ----------------
extern "C" void kernel_launch(void* const* d_in, const int* in_sizes, int n_in,
                              void* d_out, int out_size, void* d_ws, size_t ws_size,
                              hipStream_t stream) {
  const float* x      = (const float*)d_in[0];
  const int*   inc    = (const int*)  d_in[1];
  const float* pre_g  = (const float*)d_in[2];
  const float* pre_b  = (const float*)d_in[3];
  const float* lin1_W = (const float*)d_in[4];
  const float* lin1_b = (const float*)d_in[5];
  const float* n1_g   = (const float*)d_in[6];
  const float* n1_b   = (const float*)d_in[7];
  const float* th1    = (const float*)d_in[8];
  const float* bi1    = (const float*)d_in[9];
  const float* th2    = (const float*)d_in[10];
  const float* bi2    = (const float*)d_in[11];
  const float* n2_g   = (const float*)d_in[12];
  const float* n2_b   = (const float*)d_in[13];
  const float* lin2_W = (const float*)d_in[14];
  const float* lin2_b = (const float*)d_in[15];
  float* out = (float*)d_out;
  char* ws = (char*)d_ws;

  int* meta = (int*)ws;
  int* Dd   = meta + OFF_DD;
  int* Bd   = meta + OFF_BD;
  int* ncur = meta + OFF_NCUR;
  int* ecur = meta + OFF_ECUR;
  int* noff = meta + OFF_NOFF;
  int* eoff = meta + OFF_EOFF;
  int* nval = meta + OFF_NVAL;
  int* eval = meta + OFF_EVAL;

  float2* stats = (float2*)(ws + B_STATS);
  float* slotA = (float*)(ws + B_SLOTA);
  float* slotB = (float*)(ws + B_SLOTB);
  float* slotC = (float*)(ws + B_SLOTC);
  float* slotD = (float*)(ws + B_SLOTD);
  float* y1  = slotA;  // (ROWS,64) node-major
  float* xl2 = slotA;  // (ROWS,128) node-major
  float* xl1 = slotB;  // (ROWS,32) node-major
  float* ef2 = slotB;  // (E,B,128)
  float* ef1 = slotC;  // (E,B,32)
  float* y3  = slotC;  // (ROWS,128) node-major
  float* y2  = slotD;  // (ROWS,32) node-major

  hipMemsetAsync(ws, 0, (size_t)4 * E * sizeof(int), stream);

  k_hist<<<NNZ / 256, 256, 0, stream>>>(inc, Dd, Bd);
  k_scan<<<1, 256, 0, stream>>>(Dd, Bd, noff, eoff);
  k_fill<<<NNZ / 256, 256, 0, stream>>>(inc, noff, eoff, ncur, ecur, nval, eval);
  k_sort<<<(E + 255) / 256, 256, 0, stream>>>(noff, nval);
  k_sort<<<(E + 255) / 256, 256, 0, stream>>>(eoff, eval);

  // y1 = lin1(relu(LN(x)))  (batch-major in, node-major out)
  row_stats_k<256><<<ROWS / 4, 256, 0, stream>>>(x, stats);
  gemm_mfma<256, 64, 1, true, true, false>
      <<<ROWS / 64, 256, 0, stream>>>(x, lin1_W, lin1_b, stats, pre_g, pre_b, nullptr, y1);

  // xl1 = theta1(relu(LN(y1)))
  row_stats_k<64><<<ROWS / 4, 256, 0, stream>>>(y1, stats);
  gemm_mfma<64, 32, 0, true, false, false>
      <<<ROWS / 64, 256, 0, stream>>>(y1, th1, nullptr, stats, n1_g, n1_b, nullptr, xl1);

  // hconv1 propagation
  agg_k<32, false><<<E, 256, 0, stream>>>(xl1, eoff, eval, nullptr, ef1);
  agg_k<32, true ><<<E, 256, 0, stream>>>(ef1, noff, nval, bi1, y2);

  // xl2 = theta2(y2)
  gemm_mfma<32, 128, 0, false, false, false>
      <<<ROWS / 64, 256, 0, stream>>>(y2, th2, nullptr, nullptr, nullptr, nullptr, nullptr, xl2);

  // hconv2 propagation
  agg_k<128, false><<<E, 256, 0, stream>>>(xl2, eoff, eval, nullptr, ef2);
  agg_k<128, true ><<<E, 256, 0, stream>>>(ef2, noff, nval, bi2, y3);

  // out = x + lin2(relu(LN(y3)))  (node-major in, batch-major out)
  row_stats_k<128><<<ROWS / 4, 256, 0, stream>>>(y3, stats);
  gemm_mfma<128, 256, 2, true, true, true>
      <<<ROWS / 64, 256, 0, stream>>>(y3, lin2_W, lin2_b, stats, n2_g, n2_b, x, out);
}

// Round 3
// 243.161 us; speedup vs baseline: 3.9196x; 1.7853x over previous
//
#include <hip/hip_runtime.h>
#include <cstdint>

constexpr int B  = 64;
constexpr int N  = 1723;
constexpr int E  = 1723;
constexpr int NNZ = 16384;
constexpr int ROWS = B * N;   // 110272

typedef __bf16 bf16x8 __attribute__((ext_vector_type(8)));
typedef float  f32x4  __attribute__((ext_vector_type(4)));

// ---------------- workspace layout ----------------
constexpr size_t OFF_DD   = 0;
constexpr size_t OFF_BD   = OFF_DD + E;
constexpr size_t OFF_NCUR = OFF_BD + E;
constexpr size_t OFF_ECUR = OFF_NCUR + E;
constexpr size_t OFF_NOFF = OFF_ECUR + E;
constexpr size_t OFF_EOFF = OFF_NOFF + (E + 1);
constexpr size_t OFF_NVAL = OFF_EOFF + (E + 1);
constexpr size_t OFF_EVAL = OFF_NVAL + NNZ;

constexpr size_t B_SLOTA = 262144;
constexpr size_t SLOT_BIG = (size_t)ROWS * 128 * 4;   // 56.5 MB
constexpr size_t B_SLOTB = B_SLOTA + SLOT_BIG;
constexpr size_t B_SLOTC = B_SLOTB + SLOT_BIG;
constexpr size_t B_SLOTD = B_SLOTC + SLOT_BIG;

// ---------------- CSR build ----------------
__global__ __launch_bounds__(256) void k_hist(const int* __restrict__ inc,
                                              int* __restrict__ Dd, int* __restrict__ Bd) {
  int k = blockIdx.x * 256 + threadIdx.x;
  atomicAdd(&Dd[inc[k]], 1);
  atomicAdd(&Bd[inc[NNZ + k]], 1);
}

__global__ __launch_bounds__(256) void k_scan(const int* __restrict__ Dd, const int* __restrict__ Bd,
                                              int* __restrict__ noff, int* __restrict__ eoff) {
  __shared__ int part[256];
  const int t = threadIdx.x;
  for (int pass = 0; pass < 2; ++pass) {
    const int* cnt = pass ? Bd : Dd;
    int* off = pass ? eoff : noff;
    constexpr int CH = 7;
    int loc[CH];
    int s = 0;
    int base = t * CH;
#pragma unroll
    for (int i = 0; i < CH; ++i) {
      int idx = base + i;
      loc[i] = (idx < E) ? cnt[idx] : 0;
      s += loc[i];
    }
    part[t] = s;
    __syncthreads();
    for (int d = 1; d < 256; d <<= 1) {
      int v = (t >= d) ? part[t - d] : 0;
      __syncthreads();
      part[t] += v;
      __syncthreads();
    }
    int pre = (t > 0) ? part[t - 1] : 0;
#pragma unroll
    for (int i = 0; i < CH; ++i) {
      int idx = base + i;
      if (idx < E) off[idx] = pre;
      pre += loc[i];
    }
    if (t == 255) off[E] = pre;
    __syncthreads();
  }
}

__global__ __launch_bounds__(256) void k_fill(const int* __restrict__ inc,
                                              const int* __restrict__ noff, const int* __restrict__ eoff,
                                              int* __restrict__ ncur, int* __restrict__ ecur,
                                              int* __restrict__ nval, int* __restrict__ eval) {
  int k = blockIdx.x * 256 + threadIdx.x;
  int n = inc[k], e = inc[NNZ + k];
  int p = atomicAdd(&ecur[e], 1);
  eval[eoff[e] + p] = n;
  int q = atomicAdd(&ncur[n], 1);
  nval[noff[n] + q] = e;
}

__global__ __launch_bounds__(256) void k_sort(const int* __restrict__ off, int* __restrict__ vals) {
  int s = blockIdx.x * 256 + threadIdx.x;
  if (s >= E) return;
  int b = off[s], e = off[s + 1];
  for (int i = b + 1; i < e; ++i) {
    int v = vals[i];
    int j = i - 1;
    while (j >= b && vals[j] > v) { vals[j + 1] = vals[j]; --j; }
    vals[j + 1] = v;
  }
}

// ---------------- helpers ----------------
__device__ __forceinline__ ushort f2bf(float f) {
  uint32_t b = __float_as_uint(f);
  b += 0x7fffu + ((b >> 16) & 1u);
  return (ushort)(b >> 16);
}
__device__ __forceinline__ float bf2f(ushort u) {
  return __uint_as_float((uint32_t)u << 16);
}
union U16x8 { uint4 q; ushort s[8]; };

// ---------------- bf16 MFMA GEMM (fused LN stats + LN/relu on A, coalesced epilogue) ----------
// out[r][c] = sum_k act(A[r][k]) * W[c][k] (+bias[c]) (+skip), row remap per OUTMODE
// OUTMODE 0: row unchanged; 1: r=b*N+n -> (n*B+b); 2: r=n*B+b -> (b*N+n)
// grid.x = (ROWS/64) * NTILES, tile-fastest
template <int K, int NT, int NTILES, int OUTMODE, bool LNA, bool BIAS, bool SKIP, bool ABF, bool OBF>
__global__ __launch_bounds__(256, 2) void gemm_mfma(const void* __restrict__ Ap,
                                                    const float* __restrict__ W,
                                                    const float* __restrict__ bias,
                                                    const float* __restrict__ g,
                                                    const float* __restrict__ be,
                                                    const float* __restrict__ skip,
                                                    void* __restrict__ outp) {
  constexpr int NOUTTOT = NT * NTILES;
  constexpr int CPR = K / 8;
  constexpr int CMASK = (CPR >= 8) ? 7 : (CPR - 1);
  constexpr int SSTG = (64 + NT) * K * 2;
  constexpr int SOUT = 64 * (NT + 4) * 4;
  constexpr int SMEM = (SSTG > SOUT) ? SSTG : SOUT;
  __shared__ __align__(16) char smem[SMEM];
  __shared__ float2 stats_s[64];
  uint4* AsQ = (uint4*)smem;
  uint4* WsQ = AsQ + 64 * CPR;

  const int t = threadIdx.x;
  const int bid = blockIdx.x;
  const int tile = bid % NTILES;
  const int r0 = (bid / NTILES) * 64;
  const int c0 = tile * NT;

  // ---- fused LN stats: 4 lanes per row ----
  if constexpr (LNA) {
    const float* Af = (const float*)Ap;
    int row = t >> 2, part = t & 3;
    const float* src = Af + (size_t)(r0 + row) * K + part * (K / 4);
    float s1 = 0.f, s2 = 0.f;
#pragma unroll
    for (int i = 0; i < K / 16; ++i) {
      float4 v = *(const float4*)(src + i * 4);
      s1 += v.x + v.y + v.z + v.w;
      s2 += v.x * v.x + v.y * v.y + v.z * v.z + v.w * v.w;
    }
    s1 += __shfl_xor(s1, 1, 64); s2 += __shfl_xor(s2, 1, 64);
    s1 += __shfl_xor(s1, 2, 64); s2 += __shfl_xor(s2, 2, 64);
    if (part == 0) {
      float mu = s1 / K;
      float var = fmaxf(s2 / K - mu * mu, 0.f);
      stats_s[row] = make_float2(mu, rsqrtf(var + 1e-5f));
    }
    __syncthreads();
  }

  // ---- stage A ----
#pragma unroll
  for (int i = 0; i < 64 * CPR / 256; ++i) {
    int idx = t + i * 256;
    int row = idx / CPR, c = idx % CPR;
    U16x8 u;
    if constexpr (ABF) {
      const ushort* src = (const ushort*)Ap + (size_t)(r0 + row) * K + c * 8;
      u.q = *(const uint4*)src;
    } else {
      const float* src = (const float*)Ap + (size_t)(r0 + row) * K + c * 8;
      float4 v0 = *(const float4*)src;
      float4 v1 = *(const float4*)(src + 4);
      if constexpr (LNA) {
        float2 st = stats_s[row];
        float4 g0 = *(const float4*)(g + c * 8);
        float4 g1 = *(const float4*)(g + c * 8 + 4);
        float4 b0 = *(const float4*)(be + c * 8);
        float4 b1 = *(const float4*)(be + c * 8 + 4);
        v0.x = fmaxf(fmaf((v0.x - st.x) * st.y, g0.x, b0.x), 0.f);
        v0.y = fmaxf(fmaf((v0.y - st.x) * st.y, g0.y, b0.y), 0.f);
        v0.z = fmaxf(fmaf((v0.z - st.x) * st.y, g0.z, b0.z), 0.f);
        v0.w = fmaxf(fmaf((v0.w - st.x) * st.y, g0.w, b0.w), 0.f);
        v1.x = fmaxf(fmaf((v1.x - st.x) * st.y, g1.x, b1.x), 0.f);
        v1.y = fmaxf(fmaf((v1.y - st.x) * st.y, g1.y, b1.y), 0.f);
        v1.z = fmaxf(fmaf((v1.z - st.x) * st.y, g1.z, b1.z), 0.f);
        v1.w = fmaxf(fmaf((v1.w - st.x) * st.y, g1.w, b1.w), 0.f);
      }
      u.s[0] = f2bf(v0.x); u.s[1] = f2bf(v0.y); u.s[2] = f2bf(v0.z); u.s[3] = f2bf(v0.w);
      u.s[4] = f2bf(v1.x); u.s[5] = f2bf(v1.y); u.s[6] = f2bf(v1.z); u.s[7] = f2bf(v1.w);
    }
    AsQ[row * CPR + (c ^ (row & CMASK))] = u.q;
  }
  // ---- stage W ----
#pragma unroll
  for (int i = 0; i < NT * CPR / 256; ++i) {
    int idx = t + i * 256;
    int row = idx / CPR, c = idx % CPR;
    const float* src = W + (size_t)(c0 + row) * K + c * 8;
    float4 v0 = *(const float4*)src;
    float4 v1 = *(const float4*)(src + 4);
    U16x8 u;
    u.s[0] = f2bf(v0.x); u.s[1] = f2bf(v0.y); u.s[2] = f2bf(v0.z); u.s[3] = f2bf(v0.w);
    u.s[4] = f2bf(v1.x); u.s[5] = f2bf(v1.y); u.s[6] = f2bf(v1.z); u.s[7] = f2bf(v1.w);
    WsQ[row * CPR + (c ^ (row & CMASK))] = u.q;
  }
  __syncthreads();

  // ---- MFMA: 4 waves as 2(M) x 2(N) ----
  const int lane = t & 63;
  const int w = t >> 6;
  const int lo = lane & 15, hi = lane >> 4;
  const int wm = w & 1, wn = w >> 1;
  constexpr int NF2 = NT / 32;
  f32x4 acc[2][NF2] = {};
  const int m0 = wm * 32 + lo;
  const int m1 = wm * 32 + 16 + lo;
  const bf16x8* Asv = (const bf16x8*)AsQ;
  const bf16x8* Wsv = (const bf16x8*)WsQ;
#pragma unroll
  for (int ks = 0; ks < K / 32; ++ks) {
    int cb = ks * 4 + hi;
    bf16x8 a0 = Asv[m0 * CPR + (cb ^ (m0 & CMASK))];
    bf16x8 a1 = Asv[m1 * CPR + (cb ^ (m1 & CMASK))];
#pragma unroll
    for (int f = 0; f < NF2; ++f) {
      int n = wn * (NT / 2) + f * 16 + lo;
      bf16x8 bfr = Wsv[n * CPR + (cb ^ (n & CMASK))];
      acc[0][f] = __builtin_amdgcn_mfma_f32_16x16x32_bf16(a0, bfr, acc[0][f], 0, 0, 0);
      acc[1][f] = __builtin_amdgcn_mfma_f32_16x16x32_bf16(a1, bfr, acc[1][f], 0, 0, 0);
    }
  }
  __syncthreads();

  // ---- acc -> LDS (D layout: col=lane&15, row=(lane>>4)*4+reg) ----
  float* ost = (float*)smem;
  constexpr int OLD = NT + 4;
#pragma unroll
  for (int i = 0; i < 2; ++i) {
#pragma unroll
    for (int f = 0; f < NF2; ++f) {
      int col = wn * (NT / 2) + f * 16 + lo;
      float badd = BIAS ? bias[c0 + col] : 0.f;
#pragma unroll
      for (int r = 0; r < 4; ++r) {
        int lr = wm * 32 + i * 16 + hi * 4 + r;
        ost[lr * OLD + col] = acc[i][f][r] + badd;
      }
    }
  }
  __syncthreads();

  // ---- coalesced row writes ----
  if constexpr (OBF) {
    ushort* outb = (ushort*)outp;
    constexpr int C8PR = NT / 8;
#pragma unroll
    for (int i = 0; i < NT / 32; ++i) {
      int idx = t + i * 256;
      int lr = idx / C8PR, c8 = idx % C8PR;
      uint32_t r = r0 + lr;
      size_t obase = (size_t)r * NOUTTOT;  // OUTMODE 0 only for bf16 out
      U16x8 u;
#pragma unroll
      for (int j = 0; j < 8; ++j) u.s[j] = f2bf(ost[lr * OLD + c8 * 8 + j]);
      *(uint4*)(outb + obase + c0 + c8 * 8) = u.q;
    }
  } else {
    float* out = (float*)outp;
    constexpr int F4PR = NT / 4;
#pragma unroll
    for (int i = 0; i < NT / 16; ++i) {
      int idx = t + i * 256;
      int lr = idx / F4PR, c4 = idx % F4PR;
      uint32_t r = r0 + lr;
      size_t obase;
      if constexpr (OUTMODE == 0) {
        obase = (size_t)r * NOUTTOT;
      } else if constexpr (OUTMODE == 1) {
        uint32_t b_ = r / (uint32_t)N;
        uint32_t n_ = r - b_ * (uint32_t)N;
        obase = ((size_t)n_ * B + b_) * NOUTTOT;
      } else {
        uint32_t n_ = r >> 6;
        uint32_t b_ = r & 63u;
        obase = ((size_t)b_ * N + n_) * NOUTTOT;
      }
      float4 v = *(const float4*)&ost[lr * OLD + c4 * 4];
      if constexpr (SKIP) {
        float4 s = *(const float4*)(skip + obase + c0 + c4 * 4);
        v.x += s.x; v.y += s.y; v.z += s.z; v.w += s.w;
      }
      *(float4*)(out + obase + c0 + c4 * 4) = v;
    }
  }
}

// ---------------- bf16 hypergraph aggregation, C=32 (gather over CSR segment) ----------------
// out[seg] = (1/deg) * sum_{v in seg} in[v]  (+ bias)
template <bool HASB>
__global__ __launch_bounds__(256) void agg_bf16_k(const ushort* __restrict__ in,
                                                  const int* __restrict__ off,
                                                  const int* __restrict__ vals,
                                                  const float* __restrict__ bias,
                                                  ushort* __restrict__ outb) {
  const int seg = blockIdx.x;
  const int beg = off[seg], end = off[seg + 1];
  const int t = threadIdx.x;
  float acc[8] = {0.f, 0.f, 0.f, 0.f, 0.f, 0.f, 0.f, 0.f};
  for (int k = beg; k < end; ++k) {
    int src = vals[k];
    U16x8 u;
    u.q = *(const uint4*)(in + (size_t)src * 2048 + t * 8);
#pragma unroll
    for (int j = 0; j < 8; ++j) acc[j] += bf2f(u.s[j]);
  }
  float inv = (end > beg) ? 1.f / (float)(end - beg) : 0.f;
  U16x8 o;
  if constexpr (HASB) {
    int cb = (t & 3) * 8;
#pragma unroll
    for (int j = 0; j < 8; ++j) o.s[j] = f2bf(acc[j] * inv + bias[cb + j]);
  } else {
#pragma unroll
    for (int j = 0; j < 8; ++j) o.s[j] = f2bf(acc[j] * inv);
  }
  *(uint4*)(outb + (size_t)seg * 2048 + t * 8) = o.q;
}

// ---------------- launch ----------------
extern "C" void kernel_launch(void* const* d_in, const int* in_sizes, int n_in,
                              void* d_out, int out_size, void* d_ws, size_t ws_size,
                              hipStream_t stream) {
  const float* x      = (const float*)d_in[0];
  const int*   inc    = (const int*)  d_in[1];
  const float* pre_g  = (const float*)d_in[2];
  const float* pre_b  = (const float*)d_in[3];
  const float* lin1_W = (const float*)d_in[4];
  const float* lin1_b = (const float*)d_in[5];
  const float* n1_g   = (const float*)d_in[6];
  const float* n1_b   = (const float*)d_in[7];
  const float* th1    = (const float*)d_in[8];
  const float* bi1    = (const float*)d_in[9];
  const float* th2    = (const float*)d_in[10];
  const float* bi2    = (const float*)d_in[11];
  const float* n2_g   = (const float*)d_in[12];
  const float* n2_b   = (const float*)d_in[13];
  const float* lin2_W = (const float*)d_in[14];
  const float* lin2_b = (const float*)d_in[15];
  float* out = (float*)d_out;
  char* ws = (char*)d_ws;

  int* meta = (int*)ws;
  int* Dd   = meta + OFF_DD;
  int* Bd   = meta + OFF_BD;
  int* ncur = meta + OFF_NCUR;
  int* ecur = meta + OFF_ECUR;
  int* noff = meta + OFF_NOFF;
  int* eoff = meta + OFF_EOFF;
  int* nval = meta + OFF_NVAL;
  int* eval = meta + OFF_EVAL;

  float*  slotA = (float*)(ws + B_SLOTA);
  float*  slotB = (float*)(ws + B_SLOTB);
  float*  slotC = (float*)(ws + B_SLOTC);
  float*  slotD = (float*)(ws + B_SLOTD);
  float*  y1  = slotA;            // (ROWS,64) f32, node-major (n*B+b)
  float*  y3  = slotA;            // (ROWS,128) f32, node-major — y1 dead by then
  ushort* xl1 = (ushort*)slotB;   // (ROWS,32) bf16, node-major
  ushort* ef2 = (ushort*)slotB;   // (E,B,32) bf16 — xl1 dead by then
  ushort* ef1 = (ushort*)slotC;   // (E,B,32) bf16
  ushort* z   = (ushort*)slotC;   // (ROWS,32) bf16 — ef1 dead by then
  ushort* y2  = (ushort*)slotD;   // (ROWS,32) bf16

  hipMemsetAsync(ws, 0, (size_t)4 * E * sizeof(int), stream);

  k_hist<<<NNZ / 256, 256, 0, stream>>>(inc, Dd, Bd);
  k_scan<<<1, 256, 0, stream>>>(Dd, Bd, noff, eoff);
  k_fill<<<NNZ / 256, 256, 0, stream>>>(inc, noff, eoff, ncur, ecur, nval, eval);
  k_sort<<<(E + 255) / 256, 256, 0, stream>>>(noff, nval);
  k_sort<<<(E + 255) / 256, 256, 0, stream>>>(eoff, eval);

  // y1 = lin1(relu(LN(x)))   batch-major in -> node-major out
  gemm_mfma<256, 64, 1, 1, true, true, false, false, false>
      <<<ROWS / 64, 256, 0, stream>>>(x, lin1_W, lin1_b, pre_g, pre_b, nullptr, y1);

  // xl1 = theta1(relu(LN(y1)))   bf16 out
  gemm_mfma<64, 32, 1, 0, true, false, false, false, true>
      <<<ROWS / 64, 256, 0, stream>>>(y1, th1, nullptr, n1_g, n1_b, nullptr, xl1);

  // hconv1 propagation (C=32, bf16)
  agg_bf16_k<false><<<E, 256, 0, stream>>>(xl1, eoff, eval, nullptr, ef1);
  agg_bf16_k<true ><<<E, 256, 0, stream>>>(ef1, noff, nval, bi1, y2);

  // hconv2 propagation FIRST (P commutes with channel mixing), still C=32
  agg_bf16_k<false><<<E, 256, 0, stream>>>(y2, eoff, eval, nullptr, ef2);
  agg_bf16_k<false><<<E, 256, 0, stream>>>(ef2, noff, nval, nullptr, z);

  // y3 = z @ th2^T + bi2   (bf16 A)
  gemm_mfma<32, 128, 1, 0, false, true, false, true, false>
      <<<ROWS / 64, 256, 0, stream>>>(z, th2, bi2, nullptr, nullptr, nullptr, y3);

  // out = x + lin2(relu(LN(y3)))   node-major in -> batch-major out
  gemm_mfma<128, 128, 2, 2, true, true, true, false, false>
      <<<(ROWS / 64) * 2, 256, 0, stream>>>(y3, lin2_W, lin2_b, n2_g, n2_b, x, out);
}